// Round 5
// baseline (387.091 us; speedup 1.0000x reference)
//
#include <hip/hip_runtime.h>
#include <math.h>

#define Bn 4096
#define Tn 512
#define Vn 57
#define En 20
#define Hn 128
#define On 18
#define ROWS 16          // batch rows per block (= MFMA N)
#define NTHR 512         // 8 waves, one 16-col tile of h_new each
#define NBLK (Bn / ROWS) // 256 blocks -> 1 per CU
#define KEXT 160         // K = 128 (h) + 20 (emb) + 1 (bias) + 11 pad
#define KC 5             // K chunks of 32
#define HSTR 168         // h row stride (halfs): 336B, 16B-aligned, banks (20n+4q+d)%32 uniform
#define ESTR 40          // embT row stride (halfs)
#define XSTR 513         // staged x row stride (ints)

typedef _Float16 half8  __attribute__((ext_vector_type(8)));
typedef _Float16 half4  __attribute__((ext_vector_type(4)));
typedef float    floatx4 __attribute__((ext_vector_type(4)));

__device__ __forceinline__ float fast_tanh(float x) {
    float e = __expf(2.0f * x);
    return 1.0f - __fdividef(2.0f, e + 1.0f);
}

__launch_bounds__(NTHR)
__global__ void rnn_mfma_kernel(const int* __restrict__ x,
                                const int* __restrict__ xlen,
                                const float* __restrict__ emb,
                                const float* __restrict__ W_ih,
                                const float* __restrict__ W_hh,
                                const float* __restrict__ b_ih,
                                const float* __restrict__ b_hh,
                                const float* __restrict__ W_out,
                                const float* __restrict__ b_out,
                                float* __restrict__ out)
{
    __shared__ __align__(16) _Float16 sHa[2][ROWS][HSTR]; // B operand: rows=batch, cols 0..127 h, 128..159 xe(t)
    __shared__ __align__(16) _Float16 sEmb[Vn * ESTR];    // embT fp16: cols 0..19 emb, 20 = 1.0, 21..31 = 0
    __shared__ __align__(16) float    sHf[ROWS][HSTR];    // final fp32 h for epilogue
    __shared__ int sX[ROWS * XSTR];
    __shared__ float sLogit[ROWS][On];
    __shared__ float sMLS[ROWS];
    __shared__ float sPad[5600];                          // force LDS > 80KB -> 1 block/CU

    const int tid  = threadIdx.x;
    const int blk  = blockIdx.x;
    const int row0 = blk * ROWS;

    const int wave = tid >> 6;
    const int lane = tid & 63;
    const int n    = lane & 15;      // MFMA lane index (batch for B/C, W row-in-tile for A)
    const int q    = lane >> 4;      // quad
    const int jg0  = wave * 16;      // this wave's 16 h_new columns

    // ---- A operand, static in VGPRs: rows jg0+n of [W_hh | W_ih | bias | 0], fp16 hi + 2048*lo
    half8 Ah[KC], Al[KC];
    #pragma unroll
    for (int kc = 0; kc < 4; ++kc) {
        const float* wp = &W_hh[(jg0 + n) * Hn + kc * 32 + q * 8];
        #pragma unroll
        for (int i = 0; i < 8; ++i) {
            float v = wp[i];
            _Float16 hi = (_Float16)v;
            Ah[kc][i] = hi;
            Al[kc][i] = (_Float16)((v - (float)hi) * 2048.0f);
        }
    }
    {   // kc=4: W_ih (cols 0..19), bias at col 20, zeros beyond
        #pragma unroll
        for (int i = 0; i < 8; ++i) {
            int e = q * 8 + i;
            float v = 0.0f;
            if (e < En)       v = W_ih[(jg0 + n) * En + e];
            else if (e == 20) v = b_ih[jg0 + n] + b_hh[jg0 + n];
            _Float16 hi = (_Float16)v;
            Ah[4][i] = hi;
            Al[4][i] = (_Float16)((v - (float)hi) * 2048.0f);
        }
    }

    // ---- build embT (fp16) with the constant-1 bias column
    for (int idx = tid; idx < Vn * 32; idx += NTHR) {
        int c = idx >> 5, j = idx & 31;
        float v = (j < En) ? emb[c * En + j] : (j == 20 ? 1.0f : 0.0f);
        sEmb[c * ESTR + j] = (_Float16)v;
    }
    // ---- stage vocab ids
    for (int idx = tid; idx < ROWS * Tn; idx += NTHR) {
        int r = idx >> 9, t = idx & 511;
        sX[r * XSTR + t] = x[row0 * Tn + idx];
    }
    // ---- zero both h buffers (covers xe region + pad)
    for (int idx = tid; idx < 2 * ROWS * HSTR; idx += NTHR)
        ((_Float16*)sHa)[idx] = (_Float16)0.0f;
    __syncthreads();

    // ---- xe(0) staging: wave w stages batch rows 2w, 2w+1 (4 lanes x b128 each)
    const int rs  = 2 * wave + (lane >> 5);
    const int sub = lane & 31;
    {
        int id0 = sX[rs * XSTR + 0];
        if (sub < 4) {
            half8 xe = *(const half8*)&sEmb[id0 * ESTR + sub * 8];
            *(half8*)&sHa[0][rs][128 + sub * 8] = xe;
        }
    }
    __syncthreads();

    const int len_n = xlen[row0 + n];
    const int Lmax  = xlen[row0];    // sorted descending

    float hreg[4] = {0.f, 0.f, 0.f, 0.f};

    const _Float16* hrow0 = &sHa[0][0][0] + n * HSTR;   // per-lane base, parity 0
    const _Float16* hrow1 = &sHa[1][0][0] + n * HSTR;

    for (int t = 0; t < Lmax; ++t) {
        const _Float16* hb = (t & 1) ? hrow1 : hrow0;
        _Float16*       hn = (_Float16*)((t & 1) ? hrow0 : hrow1);

        // B operand: 5 contiguous b128 reads (uniform banking, 2-way pairs only)
        half8 b[KC];
        #pragma unroll
        for (int kc = 0; kc < KC; ++kc)
            b[kc] = *(const half8*)&hb[kc * 32 + q * 8];

        // stage xe(t+1) into the next buffer (8 active lanes/wave, off the critical chain)
        int tn = (t + 1 < Lmax) ? t + 1 : Lmax - 1;
        int idr = sX[rs * XSTR + tn];
        half8 xe;
        if (sub < 4)
            xe = *(const half8*)&sEmb[idr * ESTR + sub * 8];

        // D = [W_hh|W_ih|b] . [h; xe; 1]  (hi + lo/2048 split), C starts at 0
        floatx4 acch = {0.f, 0.f, 0.f, 0.f};
        floatx4 accl = {0.f, 0.f, 0.f, 0.f};
        #pragma unroll
        for (int kc = 0; kc < KC; ++kc) {
            acch = __builtin_amdgcn_mfma_f32_16x16x32_f16(Ah[kc], b[kc], acch, 0, 0, 0);
            accl = __builtin_amdgcn_mfma_f32_16x16x32_f16(Al[kc], b[kc], accl, 0, 0, 0);
        }

        // C layout: lane (n,q) reg i -> h_new[col jg0+4q+i][batch n]
        const bool upd = (t < len_n);
        half4 hsto;
        #pragma unroll
        for (int i = 0; i < 4; ++i) {
            float hv = fast_tanh(acch[i] + accl[i] * (1.0f / 2048.0f));
            hreg[i] = upd ? hv : hreg[i];
            hsto[i] = (_Float16)hreg[i];
        }
        *(half4*)&hn[jg0 + 4 * q] = hsto;   // one 8B store (4 consecutive cols of row n)

        if (sub < 4)
            *(half8*)&((t & 1) ? &sHa[0][0][0] : &sHa[1][0][0])[rs * HSTR + 128 + sub * 8] = xe;

        __syncthreads();
    }

    // ---- publish final fp32 h
    float4 hf4;
    hf4.x = hreg[0]; hf4.y = hreg[1]; hf4.z = hreg[2]; hf4.w = hreg[3];
    *(float4*)&sHf[n][jg0 + 4 * q] = hf4;
    __syncthreads();

    // ---- epilogue: logits = relu(h) @ W_out^T + b_out, then log_softmax
    for (int it = tid; it < ROWS * On; it += NTHR) {
        int r = it / On, c = it % On;
        float acc = b_out[c];
        for (int k = 0; k < Hn; ++k) {
            float hv = sHf[r][k];
            hv = hv > 0.0f ? hv : 0.0f;
            acc = fmaf(hv, W_out[c * Hn + k], acc);
        }
        sLogit[r][c] = acc;
    }
    __syncthreads();

    if (tid < ROWS) {
        float m = -INFINITY;
        #pragma unroll
        for (int c = 0; c < On; ++c) m = fmaxf(m, sLogit[tid][c]);
        float s = 0.0f;
        #pragma unroll
        for (int c = 0; c < On; ++c) s += __expf(sLogit[tid][c] - m);
        sMLS[tid] = m + __logf(s);
    }
    __syncthreads();

    for (int it = tid; it < ROWS * On; it += NTHR) {
        int r = it / On, c = it % On;
        out[(row0 + r) * On + c] = sLogit[r][c] - sMLS[r];
    }

    // keep sPad alive (never taken: xlen >= 1 always; unprovable at compile time)
    if (xlen[0] < 0) out[0] = sPad[tid];
}

extern "C" void kernel_launch(void* const* d_in, const int* in_sizes, int n_in,
                              void* d_out, int out_size, void* d_ws, size_t ws_size,
                              hipStream_t stream) {
    const int*   x     = (const int*)d_in[0];
    const int*   xlen  = (const int*)d_in[1];
    const float* emb   = (const float*)d_in[2];
    const float* W_ih  = (const float*)d_in[3];
    const float* W_hh  = (const float*)d_in[4];
    const float* b_ih  = (const float*)d_in[5];
    const float* b_hh  = (const float*)d_in[6];
    const float* W_out = (const float*)d_in[7];
    const float* b_out = (const float*)d_in[8];
    float*       out   = (float*)d_out;

    rnn_mfma_kernel<<<NBLK, NTHR, 0, stream>>>(x, xlen, emb, W_ih, W_hh,
                                               b_ih, b_hh, W_out, b_out, out);
}